// Round 1
// baseline (1034.824 us; speedup 1.0000x reference)
//
#include <hip/hip_runtime.h>

typedef short bf16x8 __attribute__((ext_vector_type(8)));
typedef float f32x4 __attribute__((ext_vector_type(4)));

#define MAX_C 400000
#define MAX_E 600000

// Module-static device scratch (BSS; zero-initialized at module load).
__device__ __align__(16) unsigned short g_W1t[128 * 384];                 // W1^T bf16 [n=128][k=384]
__device__ __align__(16) unsigned short g_W2t[128 * 128];                 // W2^T bf16 [n=128][k=128]
__device__ __align__(16) unsigned short g_cell[((size_t)MAX_C + 1) * 128];// cell_attr bf16; row MAX_C stays ZERO (mask row)
__device__ __align__(16) unsigned short g_edge[(size_t)MAX_E * 128];      // edge_attr bf16 (RNE, same bits as before)

__device__ __forceinline__ unsigned short f2bf(float f) {
    union { unsigned int i; float f; } v; v.f = f;
    return (unsigned short)((v.i + 0x7FFFu + ((v.i >> 16) & 1u)) >> 16);
}

// -------- Prep: cell scatter-sum (blocks [0,cellBlocks)) + edge bf16 convert (rest) ----
// Merged so the streaming edge convert overlaps the latency-bound cell gathers.
// cells_index is repeat(arange(C),3): cell c owns slots 3c..3c+2 -> no atomics.
// Per-cell math identical to previous passing kernel (f32 gather-sum, RNE round).
__global__ __launch_bounds__(256) void prep_kernel(
        const float* __restrict__ node_attr,
        const float* __restrict__ edge_attr,
        const int* __restrict__ cells_node,
        int C, int E, int cellBlocks)
{
    int t = threadIdx.x;
    if ((int)blockIdx.x < cellBlocks) {
        // 16 lanes per cell, 2 cells per lane-group (6 gathers in flight).
        int grp = blockIdx.x * 16 + (t >> 4);
        int sub = t & 15;
        int c0 = grp * 2, c1 = c0 + 1;
        if (c0 >= C || c0 >= MAX_C) return;
        int ja[3], jb[3];
        ja[0] = cells_node[c0 * 3 + 0];
        ja[1] = cells_node[c0 * 3 + 1];
        ja[2] = cells_node[c0 * 3 + 2];
        bool d1 = (c1 < C) && (c1 < MAX_C);
        jb[0] = d1 ? cells_node[c1 * 3 + 0] : ja[0];
        jb[1] = d1 ? cells_node[c1 * 3 + 1] : ja[1];
        jb[2] = d1 ? cells_node[c1 * 3 + 2] : ja[2];

        float a0[8] = {0.f,0.f,0.f,0.f,0.f,0.f,0.f,0.f};
        float a1[8] = {0.f,0.f,0.f,0.f,0.f,0.f,0.f,0.f};
        #pragma unroll
        for (int j = 0; j < 3; ++j) {
            const float* p = node_attr + (size_t)ja[j] * 128 + sub * 8;
            float4 v0 = *(const float4*)(p);
            float4 v1 = *(const float4*)(p + 4);
            a0[0] += v0.x; a0[1] += v0.y; a0[2] += v0.z; a0[3] += v0.w;
            a0[4] += v1.x; a0[5] += v1.y; a0[6] += v1.z; a0[7] += v1.w;
        }
        #pragma unroll
        for (int j = 0; j < 3; ++j) {
            const float* p = node_attr + (size_t)jb[j] * 128 + sub * 8;
            float4 v0 = *(const float4*)(p);
            float4 v1 = *(const float4*)(p + 4);
            a1[0] += v0.x; a1[1] += v0.y; a1[2] += v0.z; a1[3] += v0.w;
            a1[4] += v1.x; a1[5] += v1.y; a1[6] += v1.z; a1[7] += v1.w;
        }
        uint4 o0, o1;
        o0.x = (unsigned)f2bf(a0[0]) | ((unsigned)f2bf(a0[1]) << 16);
        o0.y = (unsigned)f2bf(a0[2]) | ((unsigned)f2bf(a0[3]) << 16);
        o0.z = (unsigned)f2bf(a0[4]) | ((unsigned)f2bf(a0[5]) << 16);
        o0.w = (unsigned)f2bf(a0[6]) | ((unsigned)f2bf(a0[7]) << 16);
        *(uint4*)(g_cell + (size_t)c0 * 128 + sub * 8) = o0;
        if (d1) {
            o1.x = (unsigned)f2bf(a1[0]) | ((unsigned)f2bf(a1[1]) << 16);
            o1.y = (unsigned)f2bf(a1[2]) | ((unsigned)f2bf(a1[3]) << 16);
            o1.z = (unsigned)f2bf(a1[4]) | ((unsigned)f2bf(a1[5]) << 16);
            o1.w = (unsigned)f2bf(a1[6]) | ((unsigned)f2bf(a1[7]) << 16);
            *(uint4*)(g_cell + (size_t)c1 * 128 + sub * 8) = o1;
        }
    } else {
        // Streaming edge_attr f32 -> bf16 (8 values/thread).
        long i = (long)((int)blockIdx.x - cellBlocks) * 256 + t;
        if (i >= (long)E * 16) return;
        const float* p = edge_attr + i * 8;
        float4 v0 = *(const float4*)(p);
        float4 v1 = *(const float4*)(p + 4);
        uint4 o;
        o.x = (unsigned)f2bf(v0.x) | ((unsigned)f2bf(v0.y) << 16);
        o.y = (unsigned)f2bf(v0.z) | ((unsigned)f2bf(v0.w) << 16);
        o.z = (unsigned)f2bf(v1.x) | ((unsigned)f2bf(v1.y) << 16);
        o.w = (unsigned)f2bf(v1.z) | ((unsigned)f2bf(v1.w) << 16);
        *(uint4*)(g_edge + i * 8) = o;
    }
}

// -------- Weight prep: W1 f32 [384][128] -> bf16 W1t [128][384]; W2 same ----
__global__ __launch_bounds__(256) void wprep_kernel(
        const float* __restrict__ W1,
        const float* __restrict__ W2)
{
    int i = blockIdx.x * 256 + threadIdx.x;   // grid covers 49152 + 16384
    if (i < 384 * 128) {
        int n = i / 384, k = i % 384;
        g_W1t[i] = f2bf(W1[k * 128 + n]);
    } else {
        int j = i - 384 * 128;
        int n = j / 128, k = j % 128;
        g_W2t[j] = f2bf(W2[k * 128 + n]);
    }
}

// -------- Edge MLP, operand-swapped: D = W^T * X^T --------------------------
// Block = 128 edges, 256 threads (4 waves). Wave w owns OUTPUT features
// 32w..32w+31 (2 m-tiles), all 128 edges (8 n-tiles). B-fragment of
// mfma_f32_16x16x32_bf16 is lane=column(edge), 8 contiguous k per lane ->
// edge rows (g_cell gathers / g_edge) load DIRECTLY from global as 16-B
// fragments; A-fragments are W1t/W2t rows, also direct 16-B loads (L2-hot).
// => no LDS staging and NO barriers in the whole layer-1 K-loop; gathers are
// register double-buffered (depth-1) and overlap MFMA freely.
// The only __syncthreads is around Hs (h redistribution: D-layout -> B-frags).
// Self-edge mask: masked receivers point at g_cell row MAX_C (all zeros).
__global__ __launch_bounds__(256) void edge_mlp_kernel(
        const float* __restrict__ b1,
        const float* __restrict__ b2,
        const int* __restrict__ senders,
        const int* __restrict__ receivers,
        float* __restrict__ out, int E)
{
    __shared__ __align__(16) unsigned short Hs[128][136];  // h bf16, [edge][hcol]

    const int t  = threadIdx.x;
    const int e0 = blockIdx.x * 128;
    const int wv = t >> 6;
    const int l  = t & 63;
    const int lr = l & 15;   // fragment row/col index
    const int q  = l >> 4;   // k-quad

    // Per-lane byte offsets for the 8 edge tiles this lane serves.
    unsigned os[8], orr[8], oe[8];
    #pragma unroll
    for (int nt = 0; nt < 8; ++nt) {
        int e = e0 + nt * 16 + lr;
        if (e > E - 1) e = E - 1;
        int s = senders[e];
        int r = receivers[e];
        os[nt]  = (unsigned)s * 256u;
        orr[nt] = (s == r) ? (unsigned)MAX_C * 256u : (unsigned)r * 256u;
        oe[nt]  = (unsigned)e * 256u;
    }

    const unsigned qb  = (unsigned)(q * 16);
    const unsigned ow0 = (unsigned)((wv * 32 + lr) * 768) + qb;  // W1t row, m=0
    const unsigned ow1 = ow0 + 16u * 768u;                       // m=1

    const char* cellb = (const char*)g_cell;
    const char* edgeb = (const char*)g_edge;
    const char* w1b   = (const char*)g_W1t;
    const char* w2b   = (const char*)g_W2t;

    f32x4 acc[2][8];
    #pragma unroll
    for (int m = 0; m < 2; ++m)
        #pragma unroll
        for (int nt = 0; nt < 8; ++nt) acc[m][nt] = (f32x4)(0.f);

    // Register double-buffered fragments (all indices static after unroll).
    bf16x8 aF[2][2], bF[2][8];

    auto l1load = [&](int kc, int p) {
        if (kc < 4) {                       // senders: k = 0..127
            #pragma unroll
            for (int nt = 0; nt < 8; ++nt)
                bF[p][nt] = *(const bf16x8*)(cellb + (size_t)(os[nt] + qb + kc * 64));
        } else if (kc < 8) {                // receivers (masked): k = 128..255
            #pragma unroll
            for (int nt = 0; nt < 8; ++nt)
                bF[p][nt] = *(const bf16x8*)(cellb + (size_t)(orr[nt] + qb + (kc - 4) * 64));
        } else {                            // edge_attr: k = 256..383
            #pragma unroll
            for (int nt = 0; nt < 8; ++nt)
                bF[p][nt] = *(const bf16x8*)(edgeb + (size_t)(oe[nt] + qb + (kc - 8) * 64));
        }
        aF[p][0] = *(const bf16x8*)(w1b + (size_t)(ow0 + kc * 64));
        aF[p][1] = *(const bf16x8*)(w1b + (size_t)(ow1 + kc * 64));
    };

    // ---- layer 1: K = 384 in 12 chunks, zero barriers ----
    l1load(0, 0);
    #pragma unroll
    for (int kc = 0; kc < 12; ++kc) {
        const int cur = kc & 1;
        if (kc + 1 < 12) l1load(kc + 1, cur ^ 1);
        #pragma unroll
        for (int nt = 0; nt < 8; ++nt) {
            acc[0][nt] = __builtin_amdgcn_mfma_f32_16x16x32_bf16(aF[cur][0], bF[cur][nt], acc[0][nt], 0, 0, 0);
            acc[1][nt] = __builtin_amdgcn_mfma_f32_16x16x32_bf16(aF[cur][1], bF[cur][nt], acc[1][nt], 0, 0, 0);
        }
    }

    // ---- epilogue 1: bias + relu -> Hs. D-layout gives 4 CONSECUTIVE hcols
    // per lane -> packed 8-B writes (conflict-free: banks spread by 4*lr+2q).
    #pragma unroll
    for (int m = 0; m < 2; ++m) {
        const int hc = wv * 32 + m * 16 + q * 4;
        const float4 bv = *(const float4*)(b1 + hc);
        #pragma unroll
        for (int nt = 0; nt < 8; ++nt) {
            float v0 = acc[m][nt][0] + bv.x; v0 = v0 > 0.f ? v0 : 0.f;
            float v1 = acc[m][nt][1] + bv.y; v1 = v1 > 0.f ? v1 : 0.f;
            float v2 = acc[m][nt][2] + bv.z; v2 = v2 > 0.f ? v2 : 0.f;
            float v3 = acc[m][nt][3] + bv.w; v3 = v3 > 0.f ? v3 : 0.f;
            uint2 w;
            w.x = (unsigned)f2bf(v0) | ((unsigned)f2bf(v1) << 16);
            w.y = (unsigned)f2bf(v2) | ((unsigned)f2bf(v3) << 16);
            *(uint2*)&Hs[nt * 16 + lr][hc] = w;
        }
    }

    // Prefetch all W2 A-fragments BEFORE the barrier (independent of Hs).
    const unsigned ow20 = (unsigned)((wv * 32 + lr) * 256) + qb;
    const unsigned ow21 = ow20 + 16u * 256u;
    bf16x8 w2f[2][4];
    #pragma unroll
    for (int kc = 0; kc < 4; ++kc) {
        w2f[0][kc] = *(const bf16x8*)(w2b + (size_t)(ow20 + kc * 64));
        w2f[1][kc] = *(const bf16x8*)(w2b + (size_t)(ow21 + kc * 64));
    }
    __syncthreads();   // the ONLY barrier in this kernel

    // ---- layer 2: K = 128 in 4 chunks; B-frags from Hs (stride 272 B:
    // bank-group = (lr+q)&7, perfectly even -> conflict-free b128 reads).
    f32x4 acc2[2][8];
    #pragma unroll
    for (int m = 0; m < 2; ++m)
        #pragma unroll
        for (int nt = 0; nt < 8; ++nt) acc2[m][nt] = (f32x4)(0.f);

    #pragma unroll
    for (int kc = 0; kc < 4; ++kc) {
        #pragma unroll
        for (int nt = 0; nt < 8; ++nt) {
            bf16x8 b = *(const bf16x8*)&Hs[nt * 16 + lr][kc * 32 + q * 8];
            acc2[0][nt] = __builtin_amdgcn_mfma_f32_16x16x32_bf16(w2f[0][kc], b, acc2[0][nt], 0, 0, 0);
            acc2[1][nt] = __builtin_amdgcn_mfma_f32_16x16x32_bf16(w2f[1][kc], b, acc2[1][nt], 0, 0, 0);
        }
    }

    // ---- epilogue 2: bias -> out. 4 consecutive out-cols per lane => float4
    // stores, 16 x 64-B segments per instruction (vs 4-B scatter before).
    #pragma unroll
    for (int m = 0; m < 2; ++m) {
        const int oc = wv * 32 + m * 16 + q * 4;
        const float4 bv = *(const float4*)(b2 + oc);
        #pragma unroll
        for (int nt = 0; nt < 8; ++nt) {
            int e = e0 + nt * 16 + lr;
            if (e < E) {
                float4 v;
                v.x = acc2[m][nt][0] + bv.x;
                v.y = acc2[m][nt][1] + bv.y;
                v.z = acc2[m][nt][2] + bv.z;
                v.w = acc2[m][nt][3] + bv.w;
                *(float4*)(out + (size_t)e * 128 + oc) = v;
            }
        }
    }
}

extern "C" void kernel_launch(void* const* d_in, const int* in_sizes, int n_in,
                              void* d_out, int out_size, void* d_ws, size_t ws_size,
                              hipStream_t stream)
{
    const float* node_attr = (const float*)d_in[0];
    const float* edge_attr = (const float*)d_in[1];
    const float* W1 = (const float*)d_in[2];
    const float* b1 = (const float*)d_in[3];
    const float* W2 = (const float*)d_in[4];
    const float* b2 = (const float*)d_in[5];
    const int* cells_node  = (const int*)d_in[6];
    const int* edge_index  = (const int*)d_in[8];
    float* out = (float*)d_out;

    int E = in_sizes[1] / 128;
    int C = in_sizes[6] / 3;

    const int* senders = edge_index;
    const int* receivers = edge_index + E;

    int cellBlocks = (C + 31) / 32;
    int edgeBlocks = (int)(((long)E * 16 + 255) / 256);

    hipLaunchKernelGGL(prep_kernel, dim3(cellBlocks + edgeBlocks), dim3(256), 0, stream,
                       node_attr, edge_attr, cells_node, C, E, cellBlocks);
    hipLaunchKernelGGL(wprep_kernel, dim3((384 * 128 + 128 * 128) / 256), dim3(256), 0, stream,
                       W1, W2);
    hipLaunchKernelGGL(edge_mlp_kernel, dim3((E + 127) / 128), dim3(256), 0, stream,
                       b1, b2, senders, receivers, out, E);
}

// Round 2
// 1004.315 us; speedup vs baseline: 1.0304x; 1.0304x over previous
//
#include <hip/hip_runtime.h>

typedef short bf16x8 __attribute__((ext_vector_type(8)));
typedef float f32x4 __attribute__((ext_vector_type(4)));

#define MAX_C 400000

// Module-static device scratch (BSS; zero-initialized at module load).
__device__ __align__(16) unsigned short g_W1t[128 * 384];                  // W1^T bf16 [n=128][k=384]
__device__ __align__(16) unsigned short g_W2t[128 * 128];                  // W2^T bf16 [n=128][k=128]
__device__ __align__(16) unsigned short g_cell[((size_t)MAX_C + 1) * 128]; // cell_attr bf16; row MAX_C stays ZERO (mask row)

__device__ __forceinline__ unsigned short f2bf(float f) {
    union { unsigned int i; float f; } v; v.f = f;
    return (unsigned short)((v.i + 0x7FFFu + ((v.i >> 16) & 1u)) >> 16);
}

// -------- Phase 1: cell_attr[c] = sum_{j<3} node_attr[cells_node[3c+j]] -----
// cells_index is repeat(arange(C),3): cell c owns slots 3c..3c+2 -> no atomics.
// Coalescing: lane sub reads 16B at row+sub*16 (and +256) -> every instruction
// is 16 FULL 64B-line requests (prev layout: 16 half-line requests, 2x waste).
// f32 accumulate then RNE round -> bit-identical to previous passing kernels.
__global__ __launch_bounds__(256) void cell_kernel(
        const float* __restrict__ node_attr,
        const int* __restrict__ cells_node, int C)
{
    int t = threadIdx.x;
    int grp = blockIdx.x * 16 + (t >> 4);
    int sub = t & 15;
    int c0 = grp * 2, c1 = c0 + 1;
    if (c0 >= C) return;
    bool d1 = (c1 < C);

    int ja[3], jb[3];
    ja[0] = cells_node[c0 * 3 + 0];
    ja[1] = cells_node[c0 * 3 + 1];
    ja[2] = cells_node[c0 * 3 + 2];
    jb[0] = d1 ? cells_node[c1 * 3 + 0] : ja[0];
    jb[1] = d1 ? cells_node[c1 * 3 + 1] : ja[1];
    jb[2] = d1 ? cells_node[c1 * 3 + 2] : ja[2];

    // lane sub owns floats [sub*4, sub*4+4) and [64+sub*4, 64+sub*4+4)
    float aL[4] = {0.f,0.f,0.f,0.f}, aH[4] = {0.f,0.f,0.f,0.f};
    float bL[4] = {0.f,0.f,0.f,0.f}, bH[4] = {0.f,0.f,0.f,0.f};
    #pragma unroll
    for (int j = 0; j < 3; ++j) {
        const float* r = node_attr + (size_t)ja[j] * 128;
        float4 lo = *(const float4*)(r + sub * 4);
        float4 hi = *(const float4*)(r + 64 + sub * 4);
        aL[0] += lo.x; aL[1] += lo.y; aL[2] += lo.z; aL[3] += lo.w;
        aH[0] += hi.x; aH[1] += hi.y; aH[2] += hi.z; aH[3] += hi.w;
    }
    #pragma unroll
    for (int j = 0; j < 3; ++j) {
        const float* r = node_attr + (size_t)jb[j] * 128;
        float4 lo = *(const float4*)(r + sub * 4);
        float4 hi = *(const float4*)(r + 64 + sub * 4);
        bL[0] += lo.x; bL[1] += lo.y; bL[2] += lo.z; bL[3] += lo.w;
        bH[0] += hi.x; bH[1] += hi.y; bH[2] += hi.z; bH[3] += hi.w;
    }
    uint2 o;
    o.x = (unsigned)f2bf(aL[0]) | ((unsigned)f2bf(aL[1]) << 16);
    o.y = (unsigned)f2bf(aL[2]) | ((unsigned)f2bf(aL[3]) << 16);
    *(uint2*)(g_cell + (size_t)c0 * 128 + sub * 4) = o;
    o.x = (unsigned)f2bf(aH[0]) | ((unsigned)f2bf(aH[1]) << 16);
    o.y = (unsigned)f2bf(aH[2]) | ((unsigned)f2bf(aH[3]) << 16);
    *(uint2*)(g_cell + (size_t)c0 * 128 + 64 + sub * 4) = o;
    if (d1) {
        o.x = (unsigned)f2bf(bL[0]) | ((unsigned)f2bf(bL[1]) << 16);
        o.y = (unsigned)f2bf(bL[2]) | ((unsigned)f2bf(bL[3]) << 16);
        *(uint2*)(g_cell + (size_t)c1 * 128 + sub * 4) = o;
        o.x = (unsigned)f2bf(bH[0]) | ((unsigned)f2bf(bH[1]) << 16);
        o.y = (unsigned)f2bf(bH[2]) | ((unsigned)f2bf(bH[3]) << 16);
        *(uint2*)(g_cell + (size_t)c1 * 128 + 64 + sub * 4) = o;
    }
}

// -------- Weight prep: W1 f32 [384][128] -> bf16 W1t [128][384]; W2 same ----
__global__ __launch_bounds__(256) void wprep_kernel(
        const float* __restrict__ W1,
        const float* __restrict__ W2)
{
    int i = blockIdx.x * 256 + threadIdx.x;   // grid covers 49152 + 16384
    if (i < 384 * 128) {
        int n = i / 384, k = i % 384;
        g_W1t[i] = f2bf(W1[k * 128 + n]);
    } else {
        int j = i - 384 * 128;
        int n = j / 128, k = j % 128;
        g_W2t[j] = f2bf(W2[k * 128 + n]);
    }
}

// -------- Edge MLP: D = W^T * X^T, wave owns 32 EDGES x 128 features --------
// Block = 128 edges, 4 waves; wave wv owns edges [wv*32, wv*32+32) (2 n-tiles)
// and ALL 128 output features (8 m-tiles). acc[8][2].
//   B-frags (edges, gathered): only 2/chunk -> explicit depth-2 rotating
//     prefetch fits in 48 VGPRs (round-1's 128-reg buffer collapsed; VGPR=100
//     proved the compiler serialized the loads -> MfmaUtil 7.5%).
//   A-frags (weights): same address across all waves -> L1/L2 broadcast, JIT.
//   Hs is WAVE-PRIVATE (wave writes/reads only its own 32 edge rows) ->
//     zero __syncthreads in the entire kernel.
// edge_attr read f32 directly + in-register RNE convert (g_edge pass deleted:
// it cost 461MB extra traffic to save 153MB).
__global__ __launch_bounds__(256) void edge_mlp_kernel(
        const float* __restrict__ edge_attr,
        const float* __restrict__ b1,
        const float* __restrict__ b2,
        const int* __restrict__ senders,
        const int* __restrict__ receivers,
        float* __restrict__ out, int E)
{
    __shared__ __align__(16) unsigned short Hs[128][136];  // [edge][hfeat], 272B rows

    const int t  = threadIdx.x;
    const int wv = t >> 6;
    const int l  = t & 63;
    const int lr = l & 15;   // fragment row/col index
    const int q  = l >> 4;   // k-quad
    const int e0 = blockIdx.x * 128;
    const int eb = e0 + wv * 32;

    unsigned os[2], orr[2]; int eidx[2];
    #pragma unroll
    for (int nt = 0; nt < 2; ++nt) {
        int e = eb + nt * 16 + lr;
        if (e > E - 1) e = E - 1;
        eidx[nt] = e;
        int s = senders[e];
        int r = receivers[e];
        os[nt]  = (unsigned)s * 256u;
        orr[nt] = (s == r) ? (unsigned)MAX_C * 256u : (unsigned)r * 256u;
    }

    const char* cellb = (const char*)g_cell;
    const char* w1b   = (const char*)g_W1t;
    const char* w2b   = (const char*)g_W2t;
    const unsigned qb = (unsigned)(q * 16);

    f32x4 acc[8][2];
    #pragma unroll
    for (int mt = 0; mt < 8; ++mt) { acc[mt][0] = (f32x4)(0.f); acc[mt][1] = (f32x4)(0.f); }

    // Rotating prefetch buffers (all indices static after full unroll).
    bf16x8 bB[3][2];            // cell chunks (kc < 8)
    float4 rL[3][2], rH[3][2];  // raw f32 edge chunks (kc >= 8)

    auto loadB = [&](int kc) {
        int p = kc % 3;
        if (kc < 4) {            // senders: k = 0..127, 16 rows x full 64B line
            #pragma unroll
            for (int nt = 0; nt < 2; ++nt)
                bB[p][nt] = *(const bf16x8*)(cellb + (size_t)(os[nt] + qb + kc * 64));
        } else if (kc < 8) {     // receivers (masked via zero row): k = 128..255
            #pragma unroll
            for (int nt = 0; nt < 2; ++nt)
                bB[p][nt] = *(const bf16x8*)(cellb + (size_t)(orr[nt] + qb + (kc - 4) * 64));
        } else {                 // edge_attr f32: k = 256..383
            #pragma unroll
            for (int nt = 0; nt < 2; ++nt) {
                const float* pp = edge_attr + (size_t)eidx[nt] * 128 + (kc - 8) * 32 + q * 8;
                rL[p][nt] = *(const float4*)(pp);
                rH[p][nt] = *(const float4*)(pp + 4);
            }
        }
    };
    auto getB = [&](int kc, int nt) -> bf16x8 {
        int p = kc % 3;
        if (kc < 8) return bB[p][nt];
        union { unsigned short u[8]; bf16x8 v; } r;
        float4 lo = rL[p][nt], hi = rH[p][nt];
        r.u[0] = f2bf(lo.x); r.u[1] = f2bf(lo.y); r.u[2] = f2bf(lo.z); r.u[3] = f2bf(lo.w);
        r.u[4] = f2bf(hi.x); r.u[5] = f2bf(hi.y); r.u[6] = f2bf(hi.z); r.u[7] = f2bf(hi.w);
        return r.v;
    };

    // ---- layer 1: K = 384 in 12 chunks, depth-2 gather prefetch, 0 barriers
    loadB(0); loadB(1);
    #pragma unroll
    for (int kc = 0; kc < 12; ++kc) {
        if (kc + 2 < 12) loadB(kc + 2);
        bf16x8 bb0 = getB(kc, 0);
        bf16x8 bb1 = getB(kc, 1);
        #pragma unroll
        for (int mt = 0; mt < 8; ++mt) {
            bf16x8 a = *(const bf16x8*)(w1b + (size_t)((mt * 16 + lr) * 768 + kc * 64 + qb));
            acc[mt][0] = __builtin_amdgcn_mfma_f32_16x16x32_bf16(a, bb0, acc[mt][0], 0, 0, 0);
            acc[mt][1] = __builtin_amdgcn_mfma_f32_16x16x32_bf16(a, bb1, acc[mt][1], 0, 0, 0);
        }
    }

    // ---- epilogue 1: bias + relu -> Hs (wave-private rows; aligned uint2) --
    #pragma unroll
    for (int mt = 0; mt < 8; ++mt) {
        const int f = mt * 16 + q * 4;
        const float4 bv = *(const float4*)(b1 + f);
        #pragma unroll
        for (int nt = 0; nt < 2; ++nt) {
            int el = wv * 32 + nt * 16 + lr;
            float v0 = acc[mt][nt][0] + bv.x; v0 = v0 > 0.f ? v0 : 0.f;
            float v1 = acc[mt][nt][1] + bv.y; v1 = v1 > 0.f ? v1 : 0.f;
            float v2 = acc[mt][nt][2] + bv.z; v2 = v2 > 0.f ? v2 : 0.f;
            float v3 = acc[mt][nt][3] + bv.w; v3 = v3 > 0.f ? v3 : 0.f;
            uint2 w;
            w.x = (unsigned)f2bf(v0) | ((unsigned)f2bf(v1) << 16);
            w.y = (unsigned)f2bf(v2) | ((unsigned)f2bf(v3) << 16);
            *(uint2*)&Hs[el][f] = w;
        }
    }
    // No __syncthreads: Hs rows [wv*32, wv*32+32) are written and read only by
    // wave wv; same-wave LDS ordering is enforced by compiler lgkmcnt.

    // ---- layer 2: K = 128 in 4 chunks; B-frags from wave-private Hs --------
    f32x4 acc2[8][2];
    #pragma unroll
    for (int mt = 0; mt < 8; ++mt) { acc2[mt][0] = (f32x4)(0.f); acc2[mt][1] = (f32x4)(0.f); }

    #pragma unroll
    for (int kc = 0; kc < 4; ++kc) {
        bf16x8 h0 = *(const bf16x8*)&Hs[wv * 32 +      lr][kc * 32 + q * 8];
        bf16x8 h1 = *(const bf16x8*)&Hs[wv * 32 + 16 + lr][kc * 32 + q * 8];
        #pragma unroll
        for (int mt = 0; mt < 8; ++mt) {
            bf16x8 a = *(const bf16x8*)(w2b + (size_t)((mt * 16 + lr) * 256 + kc * 64 + qb));
            acc2[mt][0] = __builtin_amdgcn_mfma_f32_16x16x32_bf16(a, h0, acc2[mt][0], 0, 0, 0);
            acc2[mt][1] = __builtin_amdgcn_mfma_f32_16x16x32_bf16(a, h1, acc2[mt][1], 0, 0, 0);
        }
    }

    // ---- epilogue 2: bias -> out. Lane holds 4 consecutive out-features ->
    // float4 stores; per instruction 16 edges x one FULL 64B line each. ------
    #pragma unroll
    for (int mt = 0; mt < 8; ++mt) {
        const int f = mt * 16 + q * 4;
        const float4 bv = *(const float4*)(b2 + f);
        #pragma unroll
        for (int nt = 0; nt < 2; ++nt) {
            int e = eb + nt * 16 + lr;
            if (e < E) {
                float4 v;
                v.x = acc2[mt][nt][0] + bv.x;
                v.y = acc2[mt][nt][1] + bv.y;
                v.z = acc2[mt][nt][2] + bv.z;
                v.w = acc2[mt][nt][3] + bv.w;
                *(float4*)(out + (size_t)e * 128 + f) = v;
            }
        }
    }
}

extern "C" void kernel_launch(void* const* d_in, const int* in_sizes, int n_in,
                              void* d_out, int out_size, void* d_ws, size_t ws_size,
                              hipStream_t stream)
{
    const float* node_attr = (const float*)d_in[0];
    const float* edge_attr = (const float*)d_in[1];
    const float* W1 = (const float*)d_in[2];
    const float* b1 = (const float*)d_in[3];
    const float* W2 = (const float*)d_in[4];
    const float* b2 = (const float*)d_in[5];
    const int* cells_node  = (const int*)d_in[6];
    const int* edge_index  = (const int*)d_in[8];
    float* out = (float*)d_out;

    int E = in_sizes[1] / 128;
    int C = in_sizes[6] / 3;

    const int* senders = edge_index;
    const int* receivers = edge_index + E;

    hipLaunchKernelGGL(cell_kernel, dim3((C + 31) / 32), dim3(256), 0, stream,
                       node_attr, cells_node, C);
    hipLaunchKernelGGL(wprep_kernel, dim3(256), dim3(256), 0, stream, W1, W2);
    hipLaunchKernelGGL(edge_mlp_kernel, dim3((E + 127) / 128), dim3(256), 0, stream,
                       edge_attr, b1, b2, senders, receivers, out, E);
}